// Round 14
// baseline (180.922 us; speedup 1.0000x reference)
//
#include <hip/hip_runtime.h>
#include <hip/hip_fp16.h>

// NCN fused per (b,h,chalf): 256 blocks x 256 thr. Block = 4 waves = 4
// c-chains, 64 lanes = d. All 4 modules in one kernel; mix only in LDS.
// Pipelined: double-buffered YL/MX, ONE barrier per chunk; gemm(ch+1) +
// stage(ch+2) + prefetch(ch+3) hide under the serial 32-step scan(ch).
// Y-HANDOFF (fix of R12 race): y f16 lives in d_ws (dense 2KB rows) when
// ws_size allows; module 3's scan then writes f32 directly to d_out, which
// NOTHING reads -> no cross-head clobber. Fallback (small ws): R11-proven
// layout (y f16 in first 2KB of d_out rows, module 3 writes f16, expand
// kernel converts to f32). MFMA mapping = R8-validated.

typedef _Float16 f16;
typedef _Float16 half8 __attribute__((ext_vector_type(8)));
typedef _Float16 half4v __attribute__((ext_vector_type(4)));
typedef float f32x4 __attribute__((ext_vector_type(4)));
typedef unsigned uint4v __attribute__((ext_vector_type(4)));

constexpr int B = 8, T = 4096, D = 1024, H = 16, DH = 64, NC = 8, NM = 4;
constexpr int CH = 256;               // t-rows per chunk
constexpr int NCHUNK = T / CH;        // 16
constexpr int YLSZ = 128 * 128;       // 16KB staged rows
constexpr int MXSZ = 64 * 256;        // 16KB mix [e][c'*64B + k*2B]
constexpr size_t YWS_BYTES = (size_t)B * T * 2048;   // 64 MiB

template <bool YWS>
__global__ __launch_bounds__(256, 1)
void ncn_main(const float* __restrict__ x, const float* __restrict__ xa,
              const float* __restrict__ w, float* __restrict__ out,
              unsigned char* __restrict__ ybuf) {
  constexpr int YROW = YWS ? 2048 : 4096;   // y f16 row stride in ybuf
  __shared__ __align__(16) unsigned char YL[2 * YLSZ];
  __shared__ __align__(16) unsigned char MX[2 * MXSZ];

  const int tid = threadIdx.x, lane = tid & 63, wv = tid >> 6;
  const int bx = blockIdx.x;                // (b:8)(h:16)(chalf:2)
  const int chalf = bx & 1, h = (bx >> 1) & 15, b = bx >> 5;
  const int cbase = chalf * 4;
  const int lr = lane & 15, lg = lane >> 4;
  const int c = cbase + wv, d = lane;

  unsigned char* const rows = (unsigned char*)out + (size_t)b * T * 4096;
  const unsigned char* const xrows =
      (const unsigned char*)x + (size_t)b * T * 4096;
  unsigned char* const ybase = ybuf + (size_t)b * T * YROW;

  float cache = xa[((size_t)b * NC + c) * D + h * DH + d];

  uint4v pf[8];
  half8 Wf[4][2];
  float mixf[32];

  auto prefetch = [&](int m, int t1) {
    if (m == 0) {
#pragma unroll
      for (int i = 0; i < 8; ++i) {
        const int gid = i * 256 + tid;
        const int c16 = gid & 15, lt = gid >> 4;
        const int t = t1 + ((lt >> 2) << 3) + cbase + (lt & 3);
        pf[i] = *(const uint4v*)(xrows + (size_t)t * 4096 + h * 256 + c16 * 16);
      }
    } else {
#pragma unroll
      for (int i = 0; i < 4; ++i) {
        const int gid = i * 256 + tid;
        const int c16 = gid & 7, lt = gid >> 3;
        const int t = t1 + ((lt >> 2) << 3) + cbase + (lt & 3);
        pf[i] = *(const uint4v*)(ybase + (size_t)t * YROW + h * 128 + c16 * 16);
      }
    }
  };
  auto stage = [&](int m, int buf) {
    unsigned char* yb = YL + buf * YLSZ;
    if (m == 0) {
#pragma unroll
      for (int i = 0; i < 8; ++i) {
        const int gid = i * 256 + tid;
        const int c16 = gid & 15, lt = gid >> 4;
        const f32x4 v = __builtin_bit_cast(f32x4, pf[i]);
        half4v hv;
#pragma unroll
        for (int e = 0; e < 4; ++e) hv[e] = (f16)v[e];
        *(half4v*)(yb + lt * 128 + ((c16 * 8) ^ ((lt & 7) << 4))) = hv;
      }
    } else {
#pragma unroll
      for (int i = 0; i < 4; ++i) {
        const int gid = i * 256 + tid;
        const int c16 = gid & 7, lt = gid >> 3;
        *(uint4v*)(yb + lt * 128 + ((c16 * 16) ^ ((lt & 7) << 4))) = pf[i];
      }
    }
  };
  auto gemm_issue = [&](int buf, f32x4 (&acc)[2][4]) {
    const unsigned char* yb = YL + buf * YLSZ;
#pragma unroll
    for (int q = 0; q < 2; ++q) {
      const int tt = wv * 2 + q;
      const int r = tt * 16 + lr;
      half8 Xf[2];
#pragma unroll
      for (int kt = 0; kt < 2; ++kt)
        Xf[kt] = *(const half8*)(yb + r * 128 +
                                 ((kt * 64 + lg * 16) ^ ((r & 7) << 4)));
#pragma unroll
      for (int it = 0; it < 4; ++it) acc[q][it] = (f32x4){0.f, 0.f, 0.f, 0.f};
#pragma unroll
      for (int kt = 0; kt < 2; ++kt)
#pragma unroll
        for (int it = 0; it < 4; ++it)
          acc[q][it] = __builtin_amdgcn_mfma_f32_16x16x32_f16(
              Xf[kt], Wf[it][kt], acc[q][it], 0, 0, 0);
    }
  };
  auto gemm_scatter = [&](int buf, const f32x4 (&acc)[2][4]) {
    unsigned char* mb = MX + buf * MXSZ;
#pragma unroll
    for (int q = 0; q < 2; ++q) {
      const int tt = wv * 2 + q;
#pragma unroll
      for (int it = 0; it < 4; ++it) {
        const int e = it * 16 + lr;
#pragma unroll
        for (int j = 0; j < 4; ++j)
          *(f16*)(mb + e * 256 +
                  ((j * 64 + (tt * 4 + lg) * 2) ^ ((e & 7) << 4))) =
              (f16)acc[q][it][j];
      }
    }
  };
  auto scan_load = [&](int buf) {
    const unsigned char* mb = MX + buf * MXSZ;
    half8 mxr[4];
#pragma unroll
    for (int k16 = 0; k16 < 4; ++k16)
      mxr[k16] = *(const half8*)(mb + d * 256 +
                                 ((wv * 64 + k16 * 16) ^ ((d & 7) << 4)));
#pragma unroll
    for (int k = 0; k < 32; ++k) mixf[k] = (float)mxr[k >> 3][k & 7];
  };
  auto scan_run = [&](int m, int t0) {
    if (m < 3 || !YWS) {                    // y f16 -> ybuf (own head bytes)
      unsigned char* sp = ybase + (size_t)(t0 + c) * YROW + h * 128 + 2 * d;
#pragma unroll
      for (int k = 0; k < 32; ++k) {
        const float z = cache + mixf[k];    // tanh(0.5(cache+mix))
        const float E = __expf(z);
        cache = fmaf(-2.0f, __builtin_amdgcn_rcpf(E + 1.0f), 1.0f);
        *(__half*)sp = __float2half_rn(cache);
        sp += 8 * YROW;
      }
    } else {                                // module 3, ws path: f32 -> d_out
      unsigned char* sp = rows + (size_t)(t0 + c) * 4096 + h * 256 + 4 * d;
#pragma unroll
      for (int k = 0; k < 32; ++k) {
        const float z = cache + mixf[k];
        const float E = __expf(z);
        cache = fmaf(-2.0f, __builtin_amdgcn_rcpf(E + 1.0f), 1.0f);
        *(float*)sp = cache;
        sp += 8 * 4096;
      }
    }
  };

  for (int m = 0; m < NM; ++m) {
    const float* wh = w + ((size_t)m * H + h) * DH * DH;
#pragma unroll
    for (int it = 0; it < 4; ++it)
#pragma unroll
      for (int kt = 0; kt < 2; ++kt)
#pragma unroll
        for (int j = 0; j < 8; ++j)
          Wf[it][kt][j] =
              (f16)wh[(size_t)(kt * 32 + lg * 8 + j) * DH + it * 16 + lr];

    // module boundary: all waves' previous-module y stores drained
    asm volatile("s_waitcnt vmcnt(0)" ::: "memory");
    __syncthreads();

    // prologue: YL[0], YL[1], MX[0]
    prefetch(m, 0);
    stage(m, 0);
    prefetch(m, CH);
    __syncthreads();
    {
      f32x4 acc0[2][4];
      gemm_issue(0, acc0);
      gemm_scatter(0, acc0);
    }
    stage(m, 1);
    prefetch(m, 2 * CH);
    __syncthreads();

    // steady state: one barrier per chunk; scan hides gemm/stage/prefetch
    for (int ch = 0; ch < NCHUNK; ++ch) {
      const int cb = ch & 1;
      scan_load(cb);
      f32x4 acc[2][4];
      if (ch + 1 < NCHUNK) gemm_issue(cb ^ 1, acc);
      scan_run(m, ch * CH);
      if (ch + 1 < NCHUNK) gemm_scatter(cb ^ 1, acc);
      if (ch + 2 < NCHUNK) stage(m, cb);
      if (ch + 3 < NCHUNK) prefetch(m, (ch + 3) * CH);
      __syncthreads();
    }
  }

  float* ya = out + (size_t)B * T * D;
  ya[((size_t)b * NC + c) * D + h * DH + d] = cache;
}

// ---- expand (fallback path): y f16 (first 2KB of row) -> f32 rows ----
__global__ __launch_bounds__(256)
void expand(float* __restrict__ buf) {
  __shared__ __align__(16) f16 rs[4 * 1024];
  const int tid = threadIdx.x;
  unsigned char* const base = (unsigned char*)buf + (size_t)blockIdx.x * 4 * 4096;
#pragma unroll
  for (int p = 0; p < 2; ++p) {
    const int gid = p * 256 + tid;
    const int row = gid >> 7, c16 = gid & 127;
    *(uint4v*)((unsigned char*)rs + row * 2048 + c16 * 16) =
        *(const uint4v*)(base + (size_t)row * 4096 + c16 * 16);
  }
  __syncthreads();
#pragma unroll
  for (int p = 0; p < 4; ++p) {
    const int gid = p * 256 + tid;
    const int row = gid >> 8, c4 = gid & 255;
    const half4v hv = *(const half4v*)((unsigned char*)rs + row * 2048 + c4 * 8);
    f32x4 v;
#pragma unroll
    for (int e = 0; e < 4; ++e) v[e] = (float)hv[e];
    *(f32x4*)(base + (size_t)row * 4096 + c4 * 16) = v;
  }
}

extern "C" void kernel_launch(void* const* d_in, const int* in_sizes, int n_in,
                              void* d_out, int out_size, void* d_ws, size_t ws_size,
                              hipStream_t stream) {
  (void)in_sizes; (void)n_in; (void)out_size;
  const float* x  = (const float*)d_in[0];
  const float* xa = (const float*)d_in[1];
  const float* w  = (const float*)d_in[2];
  float* out = (float*)d_out;

  const bool usews = (d_ws != nullptr) && (ws_size >= YWS_BYTES);
  if (usews) {
    hipLaunchKernelGGL((ncn_main<true>), dim3(256), dim3(256), 0, stream,
                       x, xa, w, out, (unsigned char*)d_ws);
  } else {
    hipLaunchKernelGGL((ncn_main<false>), dim3(256), dim3(256), 0, stream,
                       x, xa, w, out, (unsigned char*)out);
    hipLaunchKernelGGL(expand, dim3(B * T / 4), dim3(256), 0, stream, out);
  }
}